// Round 2
// baseline (138.215 us; speedup 1.0000x reference)
//
#include <hip/hip_runtime.h>
#include <hip/hip_bf16.h>

#define NS 8192
#define NT 8192
#define NCLS 91
#define THRESH 0.75f
#define NOOBJ 90

#define TCHUNK 512
#define NCHUNK (NT / TCHUNK)   // 16

// ws layout (bytes):
//   [0 .. 32)           double acc[4] = {above_sum, above_cnt, below_sum, below_cnt}
//   [32 .. 40)          u64 flag: 0 = float32 data, 1 = bf16 data
//   [64 .. 64 + NS*8)   u64 best[NS]  packed (iou_bits<<32) | ~idx

__device__ __forceinline__ float bf2f(unsigned short u) {
    union { unsigned int i; float f; } v; v.i = ((unsigned int)u) << 16; return v.f;
}
__device__ __forceinline__ float bits2f(unsigned int b) {
    union { unsigned int i; float f; } v; v.i = b; return v.f;
}
__device__ __forceinline__ float ldp(const void* p, size_t i, unsigned long long isbf) {
    return isbf ? bf2f(((const unsigned short*)p)[i]) : ((const float*)p)[i];
}

// One wave: zero acc, detect dtype. A float32 softmax row sums to 1 +/- 1e-6;
// bf16 data misread as float32 sums to ~1.3 +/- 0.1 (exponent from odd elems,
// garbage mantissa). Threshold 1e-3 separates them by >100x either way.
__global__ __launch_bounds__(64) void detect_kernel(const void* __restrict__ ps,
                                                    unsigned long long* __restrict__ flagp,
                                                    double* __restrict__ acc) {
    const int l = threadIdx.x;
    if (l < 4) acc[l] = 0.0;
    const float* f = (const float*)ps;
    float s = f[l];
    if (l + 64 < NCLS) s += f[l + 64];
    #pragma unroll
    for (int off = 32; off > 0; off >>= 1) s += __shfl_xor(s, off, 64);
    if (l == 0) flagp[0] = (fabsf(s - 1.0f) < 1e-3f) ? 0ull : 1ull;
}

__global__ __launch_bounds__(256) void init_kernel(unsigned long long* __restrict__ best) {
    best[blockIdx.x * 256 + threadIdx.x] = 0ull;
}

__global__ __launch_bounds__(256) void iou_kernel(const void* __restrict__ bs,
                                                  const void* __restrict__ bt,
                                                  const unsigned long long* __restrict__ flagp,
                                                  unsigned long long* __restrict__ best) {
    __shared__ float tx0[TCHUNK], ty0[TCHUNK], tx1[TCHUNK], ty1[TCHUNK], ta[TCHUNK];
    const unsigned long long isbf = flagp[0];
    const int tid = threadIdx.x;
    const int s   = blockIdx.x * 256 + tid;
    const int j0  = blockIdx.y * TCHUNK;

    for (int j = tid; j < TCHUNK; j += 256) {
        float x0, y0, x1, y1;
        if (isbf) {
            const ushort4 b = ((const ushort4*)bt)[j0 + j];
            x0 = bf2f(b.x); y0 = bf2f(b.y); x1 = bf2f(b.z); y1 = bf2f(b.w);
        } else {
            const float4 b = ((const float4*)bt)[j0 + j];
            x0 = b.x; y0 = b.y; x1 = b.z; y1 = b.w;
        }
        tx0[j] = x0; ty0[j] = y0; tx1[j] = x1; ty1[j] = y1;
        ta[j]  = (x1 - x0 + 1.0f) * (y1 - y0 + 1.0f);
    }
    __syncthreads();

    float sx0, sy0, sx1, sy1;
    if (isbf) {
        const ushort4 b = ((const ushort4*)bs)[s];
        sx0 = bf2f(b.x); sy0 = bf2f(b.y); sx1 = bf2f(b.z); sy1 = bf2f(b.w);
    } else {
        const float4 b = ((const float4*)bs)[s];
        sx0 = b.x; sy0 = b.y; sx1 = b.z; sy1 = b.w;
    }
    const float sa = (sx1 - sx0 + 1.0f) * (sy1 - sy0 + 1.0f);

    float biou = -1.0f;
    int   bidx = j0;
    #pragma unroll 4
    for (int j = 0; j < TCHUNK; ++j) {
        float w = fminf(sx1, tx1[j]) - fmaxf(sx0, tx0[j]) + 1.0f;
        float h = fminf(sy1, ty1[j]) - fmaxf(sy0, ty0[j]) + 1.0f;
        w = fmaxf(w, 0.0f);
        h = fmaxf(h, 0.0f);
        const float inter = w * h;
        const float iou   = inter / (sa + ta[j] - inter);   // IEEE div, matches ref
        if (iou > biou) { biou = iou; bidx = j0 + j; }      // strict > keeps smallest idx
    }

    union { float f; unsigned int i; } u; u.f = biou;       // biou >= 0 after loop
    const unsigned long long p = ((unsigned long long)u.i << 32) | (unsigned int)(~bidx);
    atomicMax(&best[s], p);
}

// 4 waves/block, each wave handles 8 students sequentially
__global__ __launch_bounds__(256) void kl_kernel(const void* __restrict__ ps,
                                                 const void* __restrict__ pt,
                                                 const unsigned long long* __restrict__ flagp,
                                                 const unsigned long long* __restrict__ best,
                                                 double* __restrict__ acc) {
    const unsigned long long isbf = flagp[0];
    const int tid  = threadIdx.x;
    const int wave = tid >> 6;
    const int lane = tid & 63;

    float wa_sum = 0.0f, wa_cnt = 0.0f, wb_sum = 0.0f, wb_cnt = 0.0f;

    for (int k = 0; k < 8; ++k) {
        const int s = blockIdx.x * 32 + wave * 8 + k;
        const unsigned long long p = best[s];
        const float miou = bits2f((unsigned int)(p >> 32));
        const int   idx  = (int)(~(unsigned int)(p & 0xffffffffu));

        if (miou > THRESH) {
            float partial = 0.0f;
            for (int c = lane; c < NCLS; c += 64) {
                const float ptc = ldp(pt, (size_t)idx * NCLS + c, isbf);
                const float psc = ldp(ps, (size_t)s   * NCLS + c, isbf);
                if (ptc > 0.0f) partial += ptc * (__logf(ptc) - __logf(psc));
            }
            #pragma unroll
            for (int off = 32; off > 0; off >>= 1)
                partial += __shfl_xor(partial, off, 64);
            wa_sum += partial;
            wa_cnt += 1.0f;
        } else {
            const float psv = ldp(ps, (size_t)s * NCLS + NOOBJ, isbf);
            wb_sum += -__logf(psv);     // wave-uniform
            wb_cnt += 1.0f;
        }
    }

    __shared__ float red[4][4];
    if (lane == 0) {
        red[wave][0] = wa_sum; red[wave][1] = wa_cnt;
        red[wave][2] = wb_sum; red[wave][3] = wb_cnt;
    }
    __syncthreads();
    if (tid == 0) {
        float s0 = 0, s1 = 0, s2 = 0, s3 = 0;
        for (int wv = 0; wv < 4; ++wv) {
            s0 += red[wv][0]; s1 += red[wv][1];
            s2 += red[wv][2]; s3 += red[wv][3];
        }
        atomicAdd(&acc[0], (double)s0);
        atomicAdd(&acc[1], (double)s1);
        atomicAdd(&acc[2], (double)s2);
        atomicAdd(&acc[3], (double)s3);
    }
}

__global__ void final_kernel(const double* __restrict__ acc,
                             const unsigned long long* __restrict__ flagp,
                             void* __restrict__ out) {
    if (threadIdx.x == 0 && blockIdx.x == 0) {
        const double above = (acc[1] > 0.0) ? acc[0] / (acc[1] * (double)NCLS) : 0.0;
        const double below = (acc[3] > 0.0) ? acc[2] / (acc[3] * (double)NCLS) : 0.0;
        const float v = (float)(above + below);
        if (flagp[0]) ((__hip_bfloat16*)out)[0] = __float2bfloat16(v);
        else          ((float*)out)[0] = v;
    }
}

extern "C" void kernel_launch(void* const* d_in, const int* in_sizes, int n_in,
                              void* d_out, int out_size, void* d_ws, size_t ws_size,
                              hipStream_t stream) {
    const void* bs = d_in[0];
    const void* bt = d_in[1];
    const void* ps = d_in[2];
    const void* pt = d_in[3];

    double*             acc  = (double*)d_ws;
    unsigned long long* flag = (unsigned long long*)((char*)d_ws + 32);
    unsigned long long* best = (unsigned long long*)((char*)d_ws + 64);

    detect_kernel<<<1, 64, 0, stream>>>(ps, flag, acc);
    init_kernel<<<NS / 256, 256, 0, stream>>>(best);
    iou_kernel<<<dim3(NS / 256, NCHUNK), 256, 0, stream>>>(bs, bt, flag, best);
    kl_kernel<<<NS / 32, 256, 0, stream>>>(ps, pt, flag, best, acc);
    final_kernel<<<1, 64, 0, stream>>>(acc, flag, d_out);
}

// Round 3
// 103.402 us; speedup vs baseline: 1.3367x; 1.3367x over previous
//
#include <hip/hip_runtime.h>
#include <hip/hip_bf16.h>

#define NS 8192
#define NT 8192
#define NCLS 91
#define THRESH 0.75f
#define NOOBJ 90

#define TCHUNK 128
#define NCHUNK (NT / TCHUNK)   // 64

#define KLB 512                // kl blocks (16 students each)

// ws layout (bytes):
//   [0 .. 8)               u64 flag: 0 = float32 data, 1 = bf16 data
//   [64 .. 64+NS*8)        u64 best[NS]  packed (iou_bits<<32) | ~idx
//   [64+NS*8 .. +KLB*32)   double partial[KLB][4] {a_sum, a_cnt, b_sum, b_cnt}

__device__ __forceinline__ float bf2f(unsigned short u) {
    union { unsigned int i; float f; } v; v.i = ((unsigned int)u) << 16; return v.f;
}
__device__ __forceinline__ float bits2f(unsigned int b) {
    union { unsigned int i; float f; } v; v.i = b; return v.f;
}
__device__ __forceinline__ float ldp(const void* p, size_t i, unsigned long long isbf) {
    return isbf ? bf2f(((const unsigned short*)p)[i]) : ((const float*)p)[i];
}

// blocks 0..31 zero best[]; block 32 wave 0 detects dtype (same logic as the
// round-2 passing run: float32 softmax row sums to 1 +/- 1e-3).
__global__ __launch_bounds__(256) void setup_kernel(const void* __restrict__ ps,
                                                    unsigned long long* __restrict__ flagp,
                                                    unsigned long long* __restrict__ best) {
    const int b = blockIdx.x;
    if (b < 32) {
        best[b * 256 + threadIdx.x] = 0ull;
    } else if (threadIdx.x < 64) {
        const int l = threadIdx.x;
        const float* f = (const float*)ps;
        float s = f[l];
        if (l + 64 < NCLS) s += f[l + 64];
        #pragma unroll
        for (int off = 32; off > 0; off >>= 1) s += __shfl_xor(s, off, 64);
        if (l == 0) flagp[0] = (fabsf(s - 1.0f) < 1e-3f) ? 0ull : 1ull;
    }
}

__global__ __launch_bounds__(256) void iou_kernel(const void* __restrict__ bs,
                                                  const void* __restrict__ bt,
                                                  const unsigned long long* __restrict__ flagp,
                                                  unsigned long long* __restrict__ best) {
    __shared__ __align__(16) float tx0[TCHUNK], ty0[TCHUNK], tx1[TCHUNK], ty1[TCHUNK], ta[TCHUNK];
    const unsigned long long isbf = flagp[0];
    const int tid = threadIdx.x;
    const int s   = blockIdx.x * 256 + tid;
    const int j0  = blockIdx.y * TCHUNK;

    for (int j = tid; j < TCHUNK; j += 256) {
        float x0, y0, x1, y1;
        if (isbf) {
            const ushort4 b = ((const ushort4*)bt)[j0 + j];
            x0 = bf2f(b.x); y0 = bf2f(b.y); x1 = bf2f(b.z); y1 = bf2f(b.w);
        } else {
            const float4 b = ((const float4*)bt)[j0 + j];
            x0 = b.x; y0 = b.y; x1 = b.z; y1 = b.w;
        }
        tx0[j] = x0; ty0[j] = y0; tx1[j] = x1; ty1[j] = y1;
        ta[j]  = (x1 - x0 + 1.0f) * (y1 - y0 + 1.0f);
    }
    __syncthreads();

    float sx0, sy0, sx1, sy1;
    if (isbf) {
        const ushort4 b = ((const ushort4*)bs)[s];
        sx0 = bf2f(b.x); sy0 = bf2f(b.y); sx1 = bf2f(b.z); sy1 = bf2f(b.w);
    } else {
        const float4 b = ((const float4*)bs)[s];
        sx0 = b.x; sy0 = b.y; sx1 = b.z; sy1 = b.w;
    }
    const float sa = (sx1 - sx0 + 1.0f) * (sy1 - sy0 + 1.0f);

    // running argmax of inter/uni without division: compare inter*bu > bi*uni.
    // uni > 0 always (w,h >= 5 for every box). bi=-1,bu=1 -> first j wins.
    float bi = -1.0f, bu = 1.0f;
    int   bidx = j0;

    for (int j = 0; j < TCHUNK; j += 4) {
        const float4 X0 = *(const float4*)(tx0 + j);
        const float4 Y0 = *(const float4*)(ty0 + j);
        const float4 X1 = *(const float4*)(tx1 + j);
        const float4 Y1 = *(const float4*)(ty1 + j);
        const float4 TA = *(const float4*)(ta  + j);

        #pragma unroll
        for (int jj = 0; jj < 4; ++jj) {
            const float x0 = (&X0.x)[jj], y0 = (&Y0.x)[jj];
            const float x1 = (&X1.x)[jj], y1 = (&Y1.x)[jj];
            const float tarea = (&TA.x)[jj];
            float w = fminf(sx1, x1) - fmaxf(sx0, x0) + 1.0f;
            float h = fminf(sy1, y1) - fmaxf(sy0, y0) + 1.0f;
            w = fmaxf(w, 0.0f);
            h = fmaxf(h, 0.0f);
            const float inter = w * h;
            const float uni   = sa + tarea - inter;
            const bool  gt    = inter * bu > bi * uni;   // strict: keep first max
            bi   = gt ? inter   : bi;
            bu   = gt ? uni     : bu;
            bidx = gt ? j0 + j + jj : bidx;
        }
    }

    union { float f; unsigned int i; } u;
    u.f = bi / bu;                                       // one IEEE div per chunk
    const unsigned long long p = ((unsigned long long)u.i << 32) | (unsigned int)(~bidx);
    atomicMax(&best[s], p);
}

// 4 waves/block, each wave handles 4 students; per-block partials -> ws (no atomics)
__global__ __launch_bounds__(256) void kl_kernel(const void* __restrict__ ps,
                                                 const void* __restrict__ pt,
                                                 const unsigned long long* __restrict__ flagp,
                                                 const unsigned long long* __restrict__ best,
                                                 double* __restrict__ partial) {
    const unsigned long long isbf = flagp[0];
    const int tid  = threadIdx.x;
    const int wave = tid >> 6;
    const int lane = tid & 63;

    float wa_sum = 0.0f, wa_cnt = 0.0f, wb_sum = 0.0f, wb_cnt = 0.0f;

    for (int k = 0; k < 4; ++k) {
        const int s = blockIdx.x * 16 + wave * 4 + k;
        const unsigned long long p = best[s];
        const float miou = bits2f((unsigned int)(p >> 32));
        const int   idx  = (int)(~(unsigned int)(p & 0xffffffffu));

        if (miou > THRESH) {
            float part = 0.0f;
            for (int c = lane; c < NCLS; c += 64) {
                const float ptc = ldp(pt, (size_t)idx * NCLS + c, isbf);
                const float psc = ldp(ps, (size_t)s   * NCLS + c, isbf);
                if (ptc > 0.0f) part += ptc * (__logf(ptc) - __logf(psc));
            }
            #pragma unroll
            for (int off = 32; off > 0; off >>= 1)
                part += __shfl_xor(part, off, 64);
            wa_sum += part;
            wa_cnt += 1.0f;
        } else {
            const float psv = ldp(ps, (size_t)s * NCLS + NOOBJ, isbf);
            wb_sum += -__logf(psv);
            wb_cnt += 1.0f;
        }
    }

    __shared__ float red[4][4];
    if (lane == 0) {
        red[wave][0] = wa_sum; red[wave][1] = wa_cnt;
        red[wave][2] = wb_sum; red[wave][3] = wb_cnt;
    }
    __syncthreads();
    if (tid == 0) {
        float s0 = 0, s1 = 0, s2 = 0, s3 = 0;
        for (int wv = 0; wv < 4; ++wv) {
            s0 += red[wv][0]; s1 += red[wv][1];
            s2 += red[wv][2]; s3 += red[wv][3];
        }
        partial[blockIdx.x * 4 + 0] = (double)s0;
        partial[blockIdx.x * 4 + 1] = (double)s1;
        partial[blockIdx.x * 4 + 2] = (double)s2;
        partial[blockIdx.x * 4 + 3] = (double)s3;
    }
}

__global__ __launch_bounds__(256) void final_kernel(const double* __restrict__ partial,
                                                    const unsigned long long* __restrict__ flagp,
                                                    void* __restrict__ out) {
    const int tid = threadIdx.x;
    double a0 = 0, a1 = 0, a2 = 0, a3 = 0;
    for (int i = tid; i < KLB; i += 256) {
        a0 += partial[i * 4 + 0];
        a1 += partial[i * 4 + 1];
        a2 += partial[i * 4 + 2];
        a3 += partial[i * 4 + 3];
    }
    __shared__ double r0[256], r1[256], r2[256], r3[256];
    r0[tid] = a0; r1[tid] = a1; r2[tid] = a2; r3[tid] = a3;
    __syncthreads();
    for (int off = 128; off > 0; off >>= 1) {
        if (tid < off) {
            r0[tid] += r0[tid + off];
            r1[tid] += r1[tid + off];
            r2[tid] += r2[tid + off];
            r3[tid] += r3[tid + off];
        }
        __syncthreads();
    }
    if (tid == 0) {
        const double above = (r1[0] > 0.0) ? r0[0] / (r1[0] * (double)NCLS) : 0.0;
        const double below = (r3[0] > 0.0) ? r2[0] / (r3[0] * (double)NCLS) : 0.0;
        const float v = (float)(above + below);
        if (flagp[0]) ((__hip_bfloat16*)out)[0] = __float2bfloat16(v);
        else          ((float*)out)[0] = v;
    }
}

extern "C" void kernel_launch(void* const* d_in, const int* in_sizes, int n_in,
                              void* d_out, int out_size, void* d_ws, size_t ws_size,
                              hipStream_t stream) {
    const void* bs = d_in[0];
    const void* bt = d_in[1];
    const void* ps = d_in[2];
    const void* pt = d_in[3];

    unsigned long long* flag = (unsigned long long*)d_ws;
    unsigned long long* best = (unsigned long long*)((char*)d_ws + 64);
    double* partial = (double*)((char*)d_ws + 64 + (size_t)NS * 8);

    setup_kernel<<<33, 256, 0, stream>>>(ps, flag, best);
    iou_kernel<<<dim3(NS / 256, NCHUNK), 256, 0, stream>>>(bs, bt, flag, best);
    kl_kernel<<<KLB, 256, 0, stream>>>(ps, pt, flag, best, partial);
    final_kernel<<<1, 256, 0, stream>>>(partial, flag, d_out);
}

// Round 4
// 100.315 us; speedup vs baseline: 1.3778x; 1.0308x over previous
//
#include <hip/hip_runtime.h>
#include <hip/hip_bf16.h>

#define NS 8192
#define NT 8192
#define NCLS 91
#define THRESH 0.75f
#define NOOBJ 90

#define TCHUNK 128
#define NCHUNK (NT / TCHUNK)   // 64
#define SPT 2                  // students per thread
#define SBLK (256 * SPT)       // students per block = 512

#define KLB 512                // kl blocks (16 students each)

// ws layout (bytes):
//   [0 .. 8)               u64 flag: 0 = float32 data, 1 = bf16 data
//   [64 .. 64+NS*8)        u64 best[NS]  packed (iou_bits<<32) | ~idx
//   [64+NS*8 .. +KLB*32)   double partial[KLB][4] {a_sum, a_cnt, b_sum, b_cnt}

__device__ __forceinline__ float bf2f(unsigned short u) {
    union { unsigned int i; float f; } v; v.i = ((unsigned int)u) << 16; return v.f;
}
__device__ __forceinline__ float bits2f(unsigned int b) {
    union { unsigned int i; float f; } v; v.i = b; return v.f;
}
__device__ __forceinline__ float ldp(const void* p, size_t i, unsigned long long isbf) {
    return isbf ? bf2f(((const unsigned short*)p)[i]) : ((const float*)p)[i];
}

// blocks 0..31 zero best[]; block 32 wave 0 detects dtype (float32 softmax row
// sums to 1 +/- 1e-3; bf16 misread as f32 does not).
__global__ __launch_bounds__(256) void setup_kernel(const void* __restrict__ ps,
                                                    unsigned long long* __restrict__ flagp,
                                                    unsigned long long* __restrict__ best) {
    const int b = blockIdx.x;
    if (b < 32) {
        best[b * 256 + threadIdx.x] = 0ull;
    } else if (threadIdx.x < 64) {
        const int l = threadIdx.x;
        const float* f = (const float*)ps;
        float s = f[l];
        if (l + 64 < NCLS) s += f[l + 64];
        #pragma unroll
        for (int off = 32; off > 0; off >>= 1) s += __shfl_xor(s, off, 64);
        if (l == 0) flagp[0] = (fabsf(s - 1.0f) < 1e-3f) ? 0ull : 1ull;
    }
}

__global__ __launch_bounds__(256) void iou_kernel(const void* __restrict__ bs,
                                                  const void* __restrict__ bt,
                                                  const unsigned long long* __restrict__ flagp,
                                                  unsigned long long* __restrict__ best) {
    // tx1p/ty1p hold x1+1, y1+1 so the inner loop skips the +1.0f adds.
    __shared__ __align__(16) float tx0[TCHUNK], ty0[TCHUNK], tx1p[TCHUNK], ty1p[TCHUNK], ta[TCHUNK];
    const unsigned long long isbf = flagp[0];
    const int tid = threadIdx.x;
    const int j0  = blockIdx.y * TCHUNK;

    for (int j = tid; j < TCHUNK; j += 256) {
        float x0, y0, x1, y1;
        if (isbf) {
            const ushort4 b = ((const ushort4*)bt)[j0 + j];
            x0 = bf2f(b.x); y0 = bf2f(b.y); x1 = bf2f(b.z); y1 = bf2f(b.w);
        } else {
            const float4 b = ((const float4*)bt)[j0 + j];
            x0 = b.x; y0 = b.y; x1 = b.z; y1 = b.w;
        }
        tx0[j] = x0; ty0[j] = y0; tx1p[j] = x1 + 1.0f; ty1p[j] = y1 + 1.0f;
        ta[j]  = (x1 - x0 + 1.0f) * (y1 - y0 + 1.0f);
    }
    __syncthreads();

    float sx0[SPT], sy0[SPT], sx1p[SPT], sy1p[SPT], sa[SPT];
    #pragma unroll
    for (int k = 0; k < SPT; ++k) {
        const int s = blockIdx.x * SBLK + k * 256 + tid;
        float x0, y0, x1, y1;
        if (isbf) {
            const ushort4 b = ((const ushort4*)bs)[s];
            x0 = bf2f(b.x); y0 = bf2f(b.y); x1 = bf2f(b.z); y1 = bf2f(b.w);
        } else {
            const float4 b = ((const float4*)bs)[s];
            x0 = b.x; y0 = b.y; x1 = b.z; y1 = b.w;
        }
        sx0[k] = x0; sy0[k] = y0; sx1p[k] = x1 + 1.0f; sy1p[k] = y1 + 1.0f;
        sa[k]  = (x1 - x0 + 1.0f) * (y1 - y0 + 1.0f);
    }

    // running argmax of inter/uni without division: inter*bu > bi*uni.
    // uni > 0 always (boxes have w,h >= 5). bi=-1,bu=1 -> first j wins.
    float bi[SPT], bu[SPT];
    int   bidx[SPT];
    #pragma unroll
    for (int k = 0; k < SPT; ++k) { bi[k] = -1.0f; bu[k] = 1.0f; bidx[k] = j0; }

    for (int j = 0; j < TCHUNK; j += 4) {
        const float4 X0 = *(const float4*)(tx0  + j);
        const float4 Y0 = *(const float4*)(ty0  + j);
        const float4 X1 = *(const float4*)(tx1p + j);
        const float4 Y1 = *(const float4*)(ty1p + j);
        const float4 TA = *(const float4*)(ta   + j);

        #pragma unroll
        for (int jj = 0; jj < 4; ++jj) {
            const float x0 = (&X0.x)[jj], y0 = (&Y0.x)[jj];
            const float x1 = (&X1.x)[jj], y1 = (&Y1.x)[jj];
            const float tarea = (&TA.x)[jj];
            #pragma unroll
            for (int k = 0; k < SPT; ++k) {
                const float w = fmaxf(fminf(sx1p[k], x1) - fmaxf(sx0[k], x0), 0.0f);
                const float h = fmaxf(fminf(sy1p[k], y1) - fmaxf(sy0[k], y0), 0.0f);
                const float inter = w * h;
                const float uni   = sa[k] + tarea - inter;
                const bool  gt    = inter * bu[k] > bi[k] * uni;  // strict: keep first max
                bi[k]   = gt ? inter       : bi[k];
                bu[k]   = gt ? uni         : bu[k];
                bidx[k] = gt ? j0 + j + jj : bidx[k];
            }
        }
    }

    #pragma unroll
    for (int k = 0; k < SPT; ++k) {
        const int s = blockIdx.x * SBLK + k * 256 + tid;
        union { float f; unsigned int i; } u;
        u.f = bi[k] / bu[k];                              // one IEEE div per chunk
        const unsigned long long p =
            ((unsigned long long)u.i << 32) | (unsigned int)(~bidx[k]);
        atomicMax(&best[s], p);
    }
}

// 4 waves/block, each wave handles 4 students; per-block partials -> ws (no atomics)
__global__ __launch_bounds__(256) void kl_kernel(const void* __restrict__ ps,
                                                 const void* __restrict__ pt,
                                                 const unsigned long long* __restrict__ flagp,
                                                 const unsigned long long* __restrict__ best,
                                                 double* __restrict__ partial) {
    const unsigned long long isbf = flagp[0];
    const int tid  = threadIdx.x;
    const int wave = tid >> 6;
    const int lane = tid & 63;

    float wa_sum = 0.0f, wa_cnt = 0.0f, wb_sum = 0.0f, wb_cnt = 0.0f;

    for (int k = 0; k < 4; ++k) {
        const int s = blockIdx.x * 16 + wave * 4 + k;
        const unsigned long long p = best[s];
        const float miou = bits2f((unsigned int)(p >> 32));
        const int   idx  = (int)(~(unsigned int)(p & 0xffffffffu));

        if (miou > THRESH) {
            float part = 0.0f;
            for (int c = lane; c < NCLS; c += 64) {
                const float ptc = ldp(pt, (size_t)idx * NCLS + c, isbf);
                const float psc = ldp(ps, (size_t)s   * NCLS + c, isbf);
                if (ptc > 0.0f) part += ptc * (__logf(ptc) - __logf(psc));
            }
            #pragma unroll
            for (int off = 32; off > 0; off >>= 1)
                part += __shfl_xor(part, off, 64);
            wa_sum += part;
            wa_cnt += 1.0f;
        } else {
            const float psv = ldp(ps, (size_t)s * NCLS + NOOBJ, isbf);
            wb_sum += -__logf(psv);
            wb_cnt += 1.0f;
        }
    }

    __shared__ float red[4][4];
    if (lane == 0) {
        red[wave][0] = wa_sum; red[wave][1] = wa_cnt;
        red[wave][2] = wb_sum; red[wave][3] = wb_cnt;
    }
    __syncthreads();
    if (tid == 0) {
        float s0 = 0, s1 = 0, s2 = 0, s3 = 0;
        for (int wv = 0; wv < 4; ++wv) {
            s0 += red[wv][0]; s1 += red[wv][1];
            s2 += red[wv][2]; s3 += red[wv][3];
        }
        partial[blockIdx.x * 4 + 0] = (double)s0;
        partial[blockIdx.x * 4 + 1] = (double)s1;
        partial[blockIdx.x * 4 + 2] = (double)s2;
        partial[blockIdx.x * 4 + 3] = (double)s3;
    }
}

__global__ __launch_bounds__(256) void final_kernel(const double* __restrict__ partial,
                                                    const unsigned long long* __restrict__ flagp,
                                                    void* __restrict__ out) {
    const int tid = threadIdx.x;
    double a0 = 0, a1 = 0, a2 = 0, a3 = 0;
    for (int i = tid; i < KLB; i += 256) {
        a0 += partial[i * 4 + 0];
        a1 += partial[i * 4 + 1];
        a2 += partial[i * 4 + 2];
        a3 += partial[i * 4 + 3];
    }
    __shared__ double r0[256], r1[256], r2[256], r3[256];
    r0[tid] = a0; r1[tid] = a1; r2[tid] = a2; r3[tid] = a3;
    __syncthreads();
    for (int off = 128; off > 0; off >>= 1) {
        if (tid < off) {
            r0[tid] += r0[tid + off];
            r1[tid] += r1[tid + off];
            r2[tid] += r2[tid + off];
            r3[tid] += r3[tid + off];
        }
        __syncthreads();
    }
    if (tid == 0) {
        const double above = (r1[0] > 0.0) ? r0[0] / (r1[0] * (double)NCLS) : 0.0;
        const double below = (r3[0] > 0.0) ? r2[0] / (r3[0] * (double)NCLS) : 0.0;
        const float v = (float)(above + below);
        if (flagp[0]) ((__hip_bfloat16*)out)[0] = __float2bfloat16(v);
        else          ((float*)out)[0] = v;
    }
}

extern "C" void kernel_launch(void* const* d_in, const int* in_sizes, int n_in,
                              void* d_out, int out_size, void* d_ws, size_t ws_size,
                              hipStream_t stream) {
    const void* bs = d_in[0];
    const void* bt = d_in[1];
    const void* ps = d_in[2];
    const void* pt = d_in[3];

    unsigned long long* flag = (unsigned long long*)d_ws;
    unsigned long long* best = (unsigned long long*)((char*)d_ws + 64);
    double* partial = (double*)((char*)d_ws + 64 + (size_t)NS * 8);

    setup_kernel<<<33, 256, 0, stream>>>(ps, flag, best);
    iou_kernel<<<dim3(NS / SBLK, NCHUNK), 256, 0, stream>>>(bs, bt, flag, best);
    kl_kernel<<<KLB, 256, 0, stream>>>(ps, pt, flag, best, partial);
    final_kernel<<<1, 256, 0, stream>>>(partial, flag, d_out);
}